// Round 5
// baseline (216.528 us; speedup 1.0000x reference)
//
#include <hip/hip_runtime.h>

// FitStepOutput: per-row exclusive-prefix cumsum of (1-2*x), argmin (first-min
// tie-break), midpoint of surrounding bin edges.
//
// R5: best-of-breed = R2's reg-staged coalesced->LDS-transpose structure,
// upgraded with (a) 2-deep register pipeline (loads issued TWO chunk-periods
// before their ds_write; two NAMED float4[8] banks, all indices static per
// rule #20), (b) __launch_bounds__(256,4) so ~100 VGPR -> up to 5 waves/SIMD
// (20 waves/CU) vs R2's 8 waves/CU. gload_lds staging rejected empirically
// (R3/R4 both 98 us vs R2 94.6). Scan is thread-per-row sequential fp32 in
// exact np.cumsum order -> bit-exact argmin (absmax 0.0 every round).

#define NBINS  128
#define ROWS   256          // rows per block == threads per block (4 waves)
#define CHUNK  32           // columns per chunk
#define NCHUNK (NBINS / CHUNK)   // 4

__global__ __launch_bounds__(ROWS, 4) void fitstep_kernel(
    const float* __restrict__ inp,
    const float* __restrict__ bins,
    float* __restrict__ out,
    int nrows)
{
    __shared__ float lds[2][ROWS * CHUNK];   // 2 x 32 KB

    const int t = threadIdx.x;
    const size_t rowbase = (size_t)blockIdx.x * ROWS;

    if (rowbase + ROWS <= (size_t)nrows) {
        const float* base = inp + rowbase * NBINS;

        // staging map: flat f = i*256 + t -> row r = f>>3, slot k = f&7;
        // global loads are 8-lane contiguous 128B (full L2 lines).
        float4 RA[8], RB[8];

        auto gload = [&](int c, float4 (&R)[8]) {
            #pragma unroll
            for (int i = 0; i < 8; ++i) {
                int f = i * ROWS + t;
                int r = f >> 3, k = f & 7;
                R[i] = *reinterpret_cast<const float4*>(
                    base + (size_t)r * NBINS + c * CHUNK + k * 4);
            }
        };
        auto stage = [&](float4 (&R)[8], int buf) {
            #pragma unroll
            for (int i = 0; i < 8; ++i) {
                int f = i * ROWS + t;
                int r = f >> 3, k = f & 7;
                int slot = k ^ (r & 7);        // XOR swizzle: conflict-free b128
                *reinterpret_cast<float4*>(&lds[buf][r * CHUNK + slot * 4]) = R[i];
            }
        };

        float score = 0.0f, best = 0.0f;
        int bestIdx = 0;

        // exact np.cumsum order; strict < keeps FIRST minimum (np.argmin)
        auto scan_chunk = [&](int c, int buf) {
            #pragma unroll
            for (int j = 0; j < 8; ++j) {
                const int slot = j ^ (t & 7);  // read-side of the swizzle
                float4 v = *reinterpret_cast<const float4*>(
                    &lds[buf][t * CHUNK + slot * 4]);
                int colbase = c * CHUNK + j * 4;
                score += (1.0f - 2.0f * v.x);
                if (score < best) { best = score; bestIdx = colbase + 1; }
                score += (1.0f - 2.0f * v.y);
                if (score < best) { best = score; bestIdx = colbase + 2; }
                score += (1.0f - 2.0f * v.z);
                if (score < best) { best = score; bestIdx = colbase + 3; }
                score += (1.0f - 2.0f * v.w);
                if (score < best) { best = score; bestIdx = colbase + 4; }
            }
        };

        // ---- 2-deep pipeline, fully unrolled (static reg banks) ----
        gload(0, RA);                 // issue G0
        gload(1, RB);                 // issue G1 (2 chunks in flight)
        stage(RA, 0);                 // waits vmcnt for G0 only
        __syncthreads();

        // c=0
        gload(2, RA);                 // RA free (drained to LDS); issue G2
        scan_chunk(0, 0);
        stage(RB, 1);                 // G1 landed long ago
        __syncthreads();
        // c=1
        gload(3, RB);                 // issue G3
        scan_chunk(1, 1);
        stage(RA, 0);                 // G2 had a full chunk-period to land
        __syncthreads();
        // c=2
        scan_chunk(2, 0);
        stage(RB, 1);
        __syncthreads();
        // c=3
        scan_chunk(3, 1);

        int lo = bestIdx - 1; if (lo < 0) lo = 0;
        int hi = bestIdx;     if (hi > NBINS - 1) hi = NBINS - 1;
        out[rowbase + t] = (bins[lo] + bins[hi]) * 0.5f;
    } else {
        // tail fallback (not hit for B = 1M = 4096 * 256)
        size_t row = rowbase + t;
        if (row >= (size_t)nrows) return;
        const float* rp = inp + row * NBINS;
        float score = 0.0f, best = 0.0f;
        int bestIdx = 0;
        for (int j = 0; j < NBINS; ++j) {
            score += (1.0f - 2.0f * rp[j]);
            if (score < best) { best = score; bestIdx = j + 1; }
        }
        int lo = bestIdx - 1; if (lo < 0) lo = 0;
        int hi = bestIdx;     if (hi > NBINS - 1) hi = NBINS - 1;
        out[row] = (bins[lo] + bins[hi]) * 0.5f;
    }
}

extern "C" void kernel_launch(void* const* d_in, const int* in_sizes, int n_in,
                              void* d_out, int out_size, void* d_ws, size_t ws_size,
                              hipStream_t stream)
{
    const float* inp  = (const float*)d_in[0];
    const float* bins = (const float*)d_in[1];
    float* out = (float*)d_out;

    int nrows = in_sizes[0] / NBINS;   // B = 1048576
    int grid  = (nrows + ROWS - 1) / ROWS;

    fitstep_kernel<<<grid, ROWS, 0, stream>>>(inp, bins, out, nrows);
}

// Round 6
// 177.033 us; speedup vs baseline: 1.2231x; 1.2231x over previous
//
#include <hip/hip_runtime.h>

// FitStepOutput: per-row exclusive-prefix cumsum of (1-2*x), argmin (first-min
// tie-break), midpoint of surrounding bin edges.
//
// R6: barrier-free, wave-independent, reg-staged.
//  - Each wave owns 64 rows; its LDS region (single 8 KB buffer) is
//    wave-private -> NO __syncthreads anywhere. Waves de-phase, smoothing
//    HBM demand (R2's barrier-synced bursts drained the memory queue).
//  - Single buffer per wave: the in-flight register bank R[8] is the second
//    buffer. gload(c+1) issues before scan(c); stage(c+1)'s ds_writes follow
//    scan(c)'s ds_reads in program order, and same-wave LDS ops execute in
//    order -> safe without sync.
//  - 32 KB LDS/block -> up to 5 blocks/CU (20 waves/CU) vs R2's 8 waves/CU.
//  - Swizzle on the ds_write address (slot = k ^ r0); read slot = j ^ (l&7).
//    Both sides 2-way bank aliasing = free (m136).
//  - NO launch_bounds min-waves (R5 spilled at the 128-VGPR cap: 216 us).
// Scan: thread-per-row sequential fp32, exact np.cumsum order, strict <
// keeps FIRST minimum -> bit-exact argmin (absmax 0.0 all rounds).

#define NBINS  128
#define CHUNK  32
#define NCHUNK (NBINS / CHUNK)   // 4
#define BLOCK  256               // 4 independent waves
#define WROWS  64                // rows per wave

__global__ __launch_bounds__(BLOCK) void fitstep_kernel(
    const float* __restrict__ inp,
    const float* __restrict__ bins,
    float* __restrict__ out,
    int nrows)
{
    __shared__ float lds[BLOCK / 64][WROWS * CHUNK];   // 4 waves x 8 KB = 32 KB

    const int t = threadIdx.x;
    const int w = t >> 6;            // wave id within block
    const int l = t & 63;            // lane
    const size_t rowbase = (size_t)blockIdx.x * BLOCK + (size_t)w * WROWS;

    if (rowbase + WROWS <= (size_t)nrows) {
        const float* gbase = inp + rowbase * NBINS;
        float* myLds = lds[w];

        // staging map (per wave): flat 16B-slot f = i*64 + l
        //   -> row r = 8*i + (l>>3), col-slot k = l&7.
        // 8 consecutive lanes read 128B contiguous (one full line per row).
        const int r0  = l >> 3;      // 0..7
        const int k   = l & 7;       // 0..7
        const int swz = k ^ r0;      // write-side swizzle slot (const per lane)

        float4 R[8];                 // in-flight chunk (the "second buffer")

        auto gload = [&](int c) {
            #pragma unroll
            for (int i = 0; i < 8; ++i) {
                int r = 8 * i + r0;
                R[i] = *reinterpret_cast<const float4*>(
                    gbase + (size_t)r * NBINS + c * CHUNK + k * 4);
            }
        };
        auto stage = [&]() {
            #pragma unroll
            for (int i = 0; i < 8; ++i) {
                int r = 8 * i + r0;  // r mod 8 == r0, so swz is valid for all i
                *reinterpret_cast<float4*>(&myLds[r * CHUNK + swz * 4]) = R[i];
            }
        };

        float score = 0.0f, best = 0.0f;
        int bestIdx = 0;

        // exact np.cumsum order; strict < keeps FIRST minimum (np.argmin)
        auto scan_chunk = [&](int c) {
            #pragma unroll
            for (int j = 0; j < 8; ++j) {
                const int slot = j ^ k;              // read-side of the swizzle
                float4 v = *reinterpret_cast<const float4*>(
                    &myLds[l * CHUNK + slot * 4]);
                int colbase = c * CHUNK + j * 4;
                score += (1.0f - 2.0f * v.x);
                if (score < best) { best = score; bestIdx = colbase + 1; }
                score += (1.0f - 2.0f * v.y);
                if (score < best) { best = score; bestIdx = colbase + 2; }
                score += (1.0f - 2.0f * v.z);
                if (score < best) { best = score; bestIdx = colbase + 3; }
                score += (1.0f - 2.0f * v.w);
                if (score < best) { best = score; bestIdx = colbase + 4; }
            }
        };

        // prologue
        gload(0);
        stage();                       // compiler inserts the vmcnt waits

        // main loop: gload(c+1) in flight while scanning chunk c; ds_writes
        // of stage() are program-ordered after scan's ds_reads (same wave,
        // in-order LDS pipe) -> single buffer is safe, no barriers.
        #pragma unroll
        for (int c = 0; c < NCHUNK; ++c) {
            if (c + 1 < NCHUNK) gload(c + 1);
            scan_chunk(c);
            if (c + 1 < NCHUNK) stage();
        }

        int lo = bestIdx - 1; if (lo < 0) lo = 0;
        int hi = bestIdx;     if (hi > NBINS - 1) hi = NBINS - 1;
        out[rowbase + l] = (bins[lo] + bins[hi]) * 0.5f;
    } else {
        // tail fallback (not hit for B = 1M = 4096 * 256)
        size_t row = rowbase + l;
        if (row >= (size_t)nrows) return;
        const float* rp = inp + row * NBINS;
        float score = 0.0f, best = 0.0f;
        int bestIdx = 0;
        for (int j = 0; j < NBINS; ++j) {
            score += (1.0f - 2.0f * rp[j]);
            if (score < best) { best = score; bestIdx = j + 1; }
        }
        int lo = bestIdx - 1; if (lo < 0) lo = 0;
        int hi = bestIdx;     if (hi > NBINS - 1) hi = NBINS - 1;
        out[row] = (bins[lo] + bins[hi]) * 0.5f;
    }
}

extern "C" void kernel_launch(void* const* d_in, const int* in_sizes, int n_in,
                              void* d_out, int out_size, void* d_ws, size_t ws_size,
                              hipStream_t stream)
{
    const float* inp  = (const float*)d_in[0];
    const float* bins = (const float*)d_in[1];
    float* out = (float*)d_out;

    int nrows = in_sizes[0] / NBINS;   // B = 1048576
    int grid  = (nrows + BLOCK - 1) / BLOCK;

    fitstep_kernel<<<grid, BLOCK, 0, stream>>>(inp, bins, out, nrows);
}

// Round 7
// 97.891 us; speedup vs baseline: 2.2119x; 1.8085x over previous
//
#include <hip/hip_runtime.h>

// FitStepOutput: per-row exclusive-prefix cumsum of (1-2*x), argmin (first-min
// tie-break), midpoint of surrounding bin edges.
//
// R7: champion structure (R2: reg-staged coalesced loads -> XOR-swizzled LDS,
// double-buffered, barrier-synced, thread-per-row bit-exact scan) with ONE
// change: ROWS 256 -> 128. LDS 64 KB -> 32 KB => 5 blocks/CU (10 waves/CU,
// vs R2's 8) and 2-wave barrier groups (less convoy loss). Everything else
// byte-identical to R2's logic. (R5's reg-pipeline spilled; R6's barrier-free
// let the compiler sink loads -> no overlap; gload_lds was slower: R3/R4.)

#define NBINS  128
#define ROWS   128          // rows per block == threads per block (2 waves)
#define CHUNK  32           // columns per chunk
#define NCHUNK (NBINS / CHUNK)   // 4

__global__ __launch_bounds__(ROWS) void fitstep_kernel(
    const float* __restrict__ inp,
    const float* __restrict__ bins,
    float* __restrict__ out,
    int nrows)
{
    __shared__ float lds[2][ROWS * CHUNK];   // 2 x 16 KB = 32 KB

    const int t = threadIdx.x;
    const size_t rowbase = (size_t)blockIdx.x * ROWS;

    if (rowbase + ROWS <= (size_t)nrows) {
        const float* base = inp + rowbase * NBINS;
        float4 pf[8];

        // staging map: flat 16B-slot f = i*128 + t -> row r = f>>3 = i*16+(t>>3),
        // slot k = f&7 = t&7. 8-lane groups read 128B contiguous (full lines).
        // swizzle slot = k ^ (r&7); i*16 === 0 (mod 8) so r&7 = (t>>3)&7.
        #pragma unroll
        for (int i = 0; i < 8; ++i) {
            int f = i * ROWS + t;
            int r = f >> 3, k = f & 7;
            pf[i] = *reinterpret_cast<const float4*>(base + (size_t)r * NBINS + k * 4);
        }
        #pragma unroll
        for (int i = 0; i < 8; ++i) {
            int f = i * ROWS + t;
            int r = f >> 3, k = f & 7;
            int slot = k ^ (r & 7);
            *reinterpret_cast<float4*>(&lds[0][r * CHUNK + slot * 4]) = pf[i];
        }
        __syncthreads();

        float score = 0.0f, best = 0.0f;
        int bestIdx = 0;

        for (int c = 0; c < NCHUNK; ++c) {
            const int buf = c & 1;

            // issue next chunk's global loads BEFORE scanning this one
            if (c + 1 < NCHUNK) {
                #pragma unroll
                for (int i = 0; i < 8; ++i) {
                    int f = i * ROWS + t;
                    int r = f >> 3, k = f & 7;
                    pf[i] = *reinterpret_cast<const float4*>(
                        base + (size_t)r * NBINS + (c + 1) * CHUNK + k * 4);
                }
            }

            // scan 32 columns from LDS, exact np.cumsum order, strict < for
            // first-occurrence argmin (bit-exact vs reference)
            #pragma unroll
            for (int j = 0; j < 8; ++j) {
                int slot = j ^ (t & 7);
                float4 v = *reinterpret_cast<const float4*>(
                    &lds[buf][t * CHUNK + slot * 4]);
                int colbase = c * CHUNK + j * 4;
                score += (1.0f - 2.0f * v.x);
                if (score < best) { best = score; bestIdx = colbase + 1; }
                score += (1.0f - 2.0f * v.y);
                if (score < best) { best = score; bestIdx = colbase + 2; }
                score += (1.0f - 2.0f * v.z);
                if (score < best) { best = score; bestIdx = colbase + 3; }
                score += (1.0f - 2.0f * v.w);
                if (score < best) { best = score; bestIdx = colbase + 4; }
            }

            // write next chunk into the other buffer, then barrier
            if (c + 1 < NCHUNK) {
                #pragma unroll
                for (int i = 0; i < 8; ++i) {
                    int f = i * ROWS + t;
                    int r = f >> 3, k = f & 7;
                    int slot = k ^ (r & 7);
                    *reinterpret_cast<float4*>(
                        &lds[buf ^ 1][r * CHUNK + slot * 4]) = pf[i];
                }
                __syncthreads();
            }
        }

        int lo = bestIdx - 1; if (lo < 0) lo = 0;
        int hi = bestIdx;     if (hi > NBINS - 1) hi = NBINS - 1;
        out[rowbase + t] = (bins[lo] + bins[hi]) * 0.5f;
    } else {
        // tail fallback (not hit for B = 1M = 8192 * 128)
        size_t row = rowbase + t;
        if (row >= (size_t)nrows) return;
        const float* rp = inp + row * NBINS;
        float score = 0.0f, best = 0.0f;
        int bestIdx = 0;
        for (int j = 0; j < NBINS; ++j) {
            score += (1.0f - 2.0f * rp[j]);
            if (score < best) { best = score; bestIdx = j + 1; }
        }
        int lo = bestIdx - 1; if (lo < 0) lo = 0;
        int hi = bestIdx;     if (hi > NBINS - 1) hi = NBINS - 1;
        out[row] = (bins[lo] + bins[hi]) * 0.5f;
    }
}

extern "C" void kernel_launch(void* const* d_in, const int* in_sizes, int n_in,
                              void* d_out, int out_size, void* d_ws, size_t ws_size,
                              hipStream_t stream)
{
    const float* inp  = (const float*)d_in[0];
    const float* bins = (const float*)d_in[1];
    float* out = (float*)d_out;

    int nrows = in_sizes[0] / NBINS;   // B = 1048576
    int grid  = (nrows + ROWS - 1) / ROWS;

    fitstep_kernel<<<grid, ROWS, 0, stream>>>(inp, bins, out, nrows);
}

// Round 8
// 94.730 us; speedup vs baseline: 2.2857x; 1.0334x over previous
//
#include <hip/hip_runtime.h>

// FitStepOutput: per-row exclusive-prefix cumsum of (1-2*x), argmin (first-min
// tie-break), midpoint of surrounding bin edges.
//
// FINAL (= R2 champion, 94.6 us, 5.46 TB/s effective on 516 MB traffic):
// coalesced cooperative loads -> XOR-swizzled LDS (double-buffered),
// thread-per-row sequential scan from LDS (bit-exact vs np.cumsum order),
// chunk c+1 global loads issued before scan of chunk c.
//
// A/B history: gload_lds staging (R3/R4: 98 us — per-chunk vmcnt drain),
// launch_bounds reg-pipeline (R5: 216 us — spill), barrier-free wave-private
// (R6: 177 us — compiler sinks loads, no overlap), ROWS=128 (R7: 97.9 us).
// All six variants cluster at 5.2-5.5 TB/s => this is the structure's wall.

#define NBINS 128
#define ROWS  256          // rows per block == threads per block
#define CHUNK 32           // columns per chunk
#define NCHUNK (NBINS / CHUNK)

__global__ __launch_bounds__(ROWS) void fitstep_kernel(
    const float* __restrict__ inp,
    const float* __restrict__ bins,
    float* __restrict__ out,
    int nrows)
{
    __shared__ float lds[2][ROWS * CHUNK];   // 2 x 32 KB = 64 KB

    const int t = threadIdx.x;
    const size_t rowbase = (size_t)blockIdx.x * ROWS;

    if (rowbase + ROWS <= (size_t)nrows) {
        const float* base = inp + rowbase * NBINS;
        float4 pf[8];

        // prologue: load + stage chunk 0
        // mapping: flat f = i*256 + t -> row r = f/8, float4-slot k = f%8
        // global: 8-lane groups read contiguous 128B (full L2 lines)
        #pragma unroll
        for (int i = 0; i < 8; ++i) {
            int f = i * ROWS + t;
            int r = f >> 3, k = f & 7;
            pf[i] = *reinterpret_cast<const float4*>(base + (size_t)r * NBINS + k * 4);
        }
        #pragma unroll
        for (int i = 0; i < 8; ++i) {
            int f = i * ROWS + t;
            int r = f >> 3, k = f & 7;
            int slot = k ^ (r & 7);            // XOR swizzle: conflict-free b128
            *reinterpret_cast<float4*>(&lds[0][r * CHUNK + slot * 4]) = pf[i];
        }
        __syncthreads();

        float score = 0.0f, best = 0.0f;
        int bestIdx = 0;

        for (int c = 0; c < NCHUNK; ++c) {
            const int buf = c & 1;

            // issue next chunk's global loads BEFORE scanning this one
            if (c + 1 < NCHUNK) {
                #pragma unroll
                for (int i = 0; i < 8; ++i) {
                    int f = i * ROWS + t;
                    int r = f >> 3, k = f & 7;
                    pf[i] = *reinterpret_cast<const float4*>(
                        base + (size_t)r * NBINS + (c + 1) * CHUNK + k * 4);
                }
            }

            // scan 32 columns from LDS, exact np.cumsum order, strict < for
            // first-occurrence argmin
            #pragma unroll
            for (int j = 0; j < 8; ++j) {
                int slot = j ^ (t & 7);
                float4 v = *reinterpret_cast<const float4*>(
                    &lds[buf][t * CHUNK + slot * 4]);
                int colbase = c * CHUNK + j * 4;
                score += (1.0f - 2.0f * v.x);
                if (score < best) { best = score; bestIdx = colbase + 1; }
                score += (1.0f - 2.0f * v.y);
                if (score < best) { best = score; bestIdx = colbase + 2; }
                score += (1.0f - 2.0f * v.z);
                if (score < best) { best = score; bestIdx = colbase + 3; }
                score += (1.0f - 2.0f * v.w);
                if (score < best) { best = score; bestIdx = colbase + 4; }
            }

            // write next chunk into the other buffer, then barrier
            if (c + 1 < NCHUNK) {
                #pragma unroll
                for (int i = 0; i < 8; ++i) {
                    int f = i * ROWS + t;
                    int r = f >> 3, k = f & 7;
                    int slot = k ^ (r & 7);
                    *reinterpret_cast<float4*>(
                        &lds[buf ^ 1][r * CHUNK + slot * 4]) = pf[i];
                }
                __syncthreads();
            }
        }

        int lo = bestIdx - 1; if (lo < 0) lo = 0;
        int hi = bestIdx;     if (hi > NBINS - 1) hi = NBINS - 1;
        out[rowbase + t] = (bins[lo] + bins[hi]) * 0.5f;
    } else {
        // tail fallback (not hit for B = 1M = 4096 * 256): per-thread path
        size_t row = rowbase + t;
        if (row >= (size_t)nrows) return;
        const float* rp = inp + row * NBINS;
        float score = 0.0f, best = 0.0f;
        int bestIdx = 0;
        for (int j = 0; j < NBINS; ++j) {
            score += (1.0f - 2.0f * rp[j]);
            if (score < best) { best = score; bestIdx = j + 1; }
        }
        int lo = bestIdx - 1; if (lo < 0) lo = 0;
        int hi = bestIdx;     if (hi > NBINS - 1) hi = NBINS - 1;
        out[row] = (bins[lo] + bins[hi]) * 0.5f;
    }
}

extern "C" void kernel_launch(void* const* d_in, const int* in_sizes, int n_in,
                              void* d_out, int out_size, void* d_ws, size_t ws_size,
                              hipStream_t stream)
{
    const float* inp  = (const float*)d_in[0];
    const float* bins = (const float*)d_in[1];
    float* out = (float*)d_out;

    int nrows = in_sizes[0] / NBINS;   // B = 1048576
    int grid  = (nrows + ROWS - 1) / ROWS;

    fitstep_kernel<<<grid, ROWS, 0, stream>>>(inp, bins, out, nrows);
}